// Round 2
// baseline (6530.128 us; speedup 1.0000x reference)
//
#include <hip/hip_runtime.h>
#include <hip/hip_bf16.h>
#include <stdint.h>

#define N_ATOMS 65536
#define N_BONDS 131072
#define N_MOLS  512
#define D_IN    16
#define DD      128
#define REPEAT  3

// ---------------- init kernels ----------------

// he[e][d] = relu(bo[e] * W_fe[0][d] + b_fe[d])   (initial h_e state == h_e0)
__global__ void k_init_edges(const float* __restrict__ bo, const float* __restrict__ Wfe,
                             const float* __restrict__ bfe, float* __restrict__ he) {
    int idx = blockIdx.x * 256 + threadIdx.x;     // E*D threads
    int e = idx >> 7, d = idx & 127;
    float v = fmaf(bo[e], Wfe[d], bfe[d]);
    he[idx] = fmaxf(v, 0.f);
}

// hv[n][d] = relu(sum_k atoms[n][k]*W_fv[k][d] + b_fv[d])   (initial h_v state == h_v0)
__global__ void k_init_nodes(const float* __restrict__ atoms, const float* __restrict__ Wfv,
                             const float* __restrict__ bfv, float* __restrict__ hv) {
    int idx = blockIdx.x * 256 + threadIdx.x;     // N*D threads
    int n = idx >> 7, d = idx & 127;
    float acc = bfv[d];
#pragma unroll
    for (int k = 0; k < D_IN; k++)
        acc = fmaf(atoms[n*D_IN + k], Wfv[k*DD + d], acc);
    hv[idx] = fmaxf(acc, 0.f);
}

// segment sum of fp32 [rows,128] by sorted ids -> fp32 out[?,128] (pre-zeroed)
__global__ void k_segsum(const float* __restrict__ x, const int* __restrict__ ids,
                         float* __restrict__ out, int rows, int chunk) {
    int r0 = blockIdx.x * chunk;
    int d = threadIdx.x;           // 128 threads
    int rend = min(r0 + chunk, rows);
    if (r0 >= rend) return;
    float acc = 0.f;
    int cur = ids[r0];
    for (int r = r0; r < rend; r++) {
        int m = ids[r];
        if (m != cur) { atomicAdd(&out[cur*DD + d], acc); acc = 0.f; cur = m; }
        acc += x[r*DD + d];
    }
    atomicAdd(&out[cur*DD + d], acc);
}

// h_u0[m][d] = relu(sum_k ns[m][k]*W_fu[k][d] + b_fu[d])
__global__ void k_mol_init(const float* __restrict__ ns, const float* __restrict__ Wfu,
                           const float* __restrict__ bfu, float* __restrict__ hu0) {
    int idx = blockIdx.x * 256 + threadIdx.x;    // M*D threads
    int m = idx >> 7, d = idx & 127;
    float acc = bfu[d];
    for (int k = 0; k < DD; k++)
        acc = fmaf(ns[m*DD + k], Wfu[k*DD + d], acc);
    hu0[idx] = fmaxf(acc, 0.f);
}

// ---------------- phi_e ----------------
// he[e] <- relu( [h_e | h_e0(recomputed) | h_v[src] | h_v[dst] | h_u[mol]] @ W_e + b_e )
// in-place on he; also scatter-add the relu'd output into ebar_i[src] and ebar_i[dst]
#define TE 16
#define XSE 644   // 640 padded; (644 % 32) = 4 so rows start in different banks

__global__ __launch_bounds__(256) void k_phi_e(
        float* __restrict__ he,        const float* __restrict__ bo,
        const float* __restrict__ Wfe, const float* __restrict__ bfe,
        const float* __restrict__ hv,  const float* __restrict__ hu,
        const float* __restrict__ We,  const float* __restrict__ be,
        const int* __restrict__ bsrc,  const int* __restrict__ bdst,
        const int* __restrict__ bmol,  float* __restrict__ ebar_i) {
    __shared__ float xs[TE * XSE];
    __shared__ int ssrc[TE], sdst[TE], smol[TE];
    __shared__ float sbo[TE];
    int tid = threadIdx.x;
    int e0 = blockIdx.x * TE;
    if (tid < TE) {
        ssrc[tid] = bsrc[e0 + tid];
        sdst[tid] = bdst[e0 + tid];
        smol[tid] = bmol[e0 + tid];
        sbo[tid]  = bo[e0 + tid];
    }
    __syncthreads();
    for (int t = tid; t < TE * 640; t += 256) {
        int i = t / 640;
        int k = t - i * 640;
        int seg = k >> 7, kk = k & 127;
        int e = e0 + i;
        float v;
        if      (seg == 0) v = he[e*DD + kk];
        else if (seg == 1) v = fmaxf(fmaf(sbo[i], Wfe[kk], bfe[kk]), 0.f);  // h_e0 recomputed
        else if (seg == 2) v = hv[ssrc[i]*DD + kk];
        else if (seg == 3) v = hv[sdst[i]*DD + kk];
        else               v = hu[smol[i]*DD + kk];
        xs[i*XSE + k] = v;
    }
    __syncthreads();

    int i  = tid >> 4;          // row 0..15
    int d8 = (tid & 15) * 8;    // col group
    float acc[8];
#pragma unroll
    for (int j = 0; j < 8; j++) acc[j] = be[d8 + j];

    const float* xrow = &xs[i * XSE];
    for (int k = 0; k < 640; k++) {
        float xv = xrow[k];
        float4 w0 = *reinterpret_cast<const float4*>(We + k*DD + d8);
        float4 w1 = *reinterpret_cast<const float4*>(We + k*DD + d8 + 4);
        acc[0] = fmaf(xv, w0.x, acc[0]);
        acc[1] = fmaf(xv, w0.y, acc[1]);
        acc[2] = fmaf(xv, w0.z, acc[2]);
        acc[3] = fmaf(xv, w0.w, acc[3]);
        acc[4] = fmaf(xv, w1.x, acc[4]);
        acc[5] = fmaf(xv, w1.y, acc[5]);
        acc[6] = fmaf(xv, w1.z, acc[6]);
        acc[7] = fmaf(xv, w1.w, acc[7]);
    }
    int e = e0 + i;
#pragma unroll
    for (int j = 0; j < 8; j++) acc[j] = fmaxf(acc[j], 0.f);
    float4 o0 = make_float4(acc[0], acc[1], acc[2], acc[3]);
    float4 o1 = make_float4(acc[4], acc[5], acc[6], acc[7]);
    *reinterpret_cast<float4*>(he + e*DD + d8)     = o0;
    *reinterpret_cast<float4*>(he + e*DD + d8 + 4) = o1;

    int s = ssrc[i], dd = sdst[i];
#pragma unroll
    for (int j = 0; j < 8; j++) {
        atomicAdd(&ebar_i[s*DD + d8 + j], acc[j]);
        atomicAdd(&ebar_i[dd*DD + d8 + j], acc[j]);
    }
}

// ---------------- phi_v ----------------
// hv[n] <- relu( [h_v | h_v0(recomputed) | e_bar_i[n] | h_u[amol]] @ W_v + b_v )  (in-place)
#define TN 16
#define XSV 516   // 512 padded

__global__ __launch_bounds__(256) void k_phi_v(
        float* __restrict__ hv,         const float* __restrict__ atoms,
        const float* __restrict__ Wfv,  const float* __restrict__ bfv,
        const float* __restrict__ ebar_i, const float* __restrict__ hu,
        const float* __restrict__ Wv,   const float* __restrict__ bv,
        const int* __restrict__ amol) {
    __shared__ float xs[TN * XSV];
    __shared__ float satoms[TN * D_IN];
    __shared__ int smol[TN];
    int tid = threadIdx.x;
    int n0 = blockIdx.x * TN;
    if (tid < TN) smol[tid] = amol[n0 + tid];
    if (tid < TN * D_IN) satoms[tid] = atoms[n0*D_IN + tid];
    __syncthreads();
    for (int t = tid; t < TN * 512; t += 256) {
        int i = t >> 9;
        int k = t & 511;
        int seg = k >> 7, kk = k & 127;
        int n = n0 + i;
        float v;
        if      (seg == 0) v = hv[n*DD + kk];
        else if (seg == 1) {                      // h_v0 recomputed from atoms row
            float a = bfv[kk];
#pragma unroll
            for (int j = 0; j < D_IN; j++)
                a = fmaf(satoms[i*D_IN + j], Wfv[j*DD + kk], a);
            v = fmaxf(a, 0.f);
        }
        else if (seg == 2) v = ebar_i[n*DD + kk];
        else               v = hu[smol[i]*DD + kk];
        xs[i*XSV + k] = v;
    }
    __syncthreads();

    int i  = tid >> 4;
    int d8 = (tid & 15) * 8;
    float acc[8];
#pragma unroll
    for (int j = 0; j < 8; j++) acc[j] = bv[d8 + j];

    const float* xrow = &xs[i * XSV];
    for (int k = 0; k < 512; k++) {
        float xv = xrow[k];
        float4 w0 = *reinterpret_cast<const float4*>(Wv + k*DD + d8);
        float4 w1 = *reinterpret_cast<const float4*>(Wv + k*DD + d8 + 4);
        acc[0] = fmaf(xv, w0.x, acc[0]);
        acc[1] = fmaf(xv, w0.y, acc[1]);
        acc[2] = fmaf(xv, w0.z, acc[2]);
        acc[3] = fmaf(xv, w0.w, acc[3]);
        acc[4] = fmaf(xv, w1.x, acc[4]);
        acc[5] = fmaf(xv, w1.y, acc[5]);
        acc[6] = fmaf(xv, w1.z, acc[6]);
        acc[7] = fmaf(xv, w1.w, acc[7]);
    }
    int n = n0 + i;
#pragma unroll
    for (int j = 0; j < 8; j++) acc[j] = fmaxf(acc[j], 0.f);
    float4 o0 = make_float4(acc[0], acc[1], acc[2], acc[3]);
    float4 o1 = make_float4(acc[4], acc[5], acc[6], acc[7]);
    *reinterpret_cast<float4*>(hv + n*DD + d8)     = o0;
    *reinterpret_cast<float4*>(hv + n*DD + d8 + 4) = o1;
}

// ---------------- phi_u ----------------
// out[m][d] = relu( [h_u | h_u0 | e_bar | v_bar] @ W_u + b_u ); writes fp32 state + d_out
__global__ void k_phi_u(const float* __restrict__ hu_in, const float* __restrict__ hu0,
                        const float* __restrict__ ebar, const float* __restrict__ vbar,
                        const float* __restrict__ Wu, const float* __restrict__ bu,
                        float* __restrict__ hu_out, float* __restrict__ dout) {
    int idx = blockIdx.x * 256 + threadIdx.x;   // M*D threads
    int m = idx >> 7, d = idx & 127;
    float acc = bu[d];
    const float* segs[4] = { hu_in + m*DD, hu0 + m*DD, ebar + m*DD, vbar + m*DD };
    for (int s = 0; s < 4; s++) {
        const float* x = segs[s];
        const float* W = Wu + (s*DD)*DD + d;
        for (int k = 0; k < DD; k++)
            acc = fmaf(x[k], W[k*DD], acc);
    }
    float v = fmaxf(acc, 0.f);
    hu_out[idx] = v;
    dout[idx] = v;
}

// ---------------- launch ----------------

extern "C" void kernel_launch(void* const* d_in, const int* in_sizes, int n_in,
                              void* d_out, int out_size, void* d_ws, size_t ws_size,
                              hipStream_t stream) {
    const float* atoms = (const float*)d_in[0];
    const float* bo    = (const float*)d_in[1];
    const float* Wfe   = (const float*)d_in[2];
    const float* bfe   = (const float*)d_in[3];
    const float* Wfv   = (const float*)d_in[4];
    const float* bfv   = (const float*)d_in[5];
    const float* Wfu   = (const float*)d_in[6];
    const float* bfu   = (const float*)d_in[7];
    const float* We    = (const float*)d_in[8];
    const float* be    = (const float*)d_in[9];
    const float* Wv    = (const float*)d_in[10];
    const float* bv    = (const float*)d_in[11];
    const float* Wu    = (const float*)d_in[12];
    const float* bu    = (const float*)d_in[13];
    const int* bsrc    = (const int*)d_in[14];
    const int* bdst    = (const int*)d_in[15];
    const int* amol    = (const int*)d_in[16];
    const int* bmol    = (const int*)d_in[17];

    char* p = (char*)d_ws;
    auto alloc = [&](size_t bytes) {
        char* r = p;
        p += (bytes + 255) & ~(size_t)255;
        return r;
    };
    float* he       = (float*)alloc((size_t)N_BONDS * DD * 4);   // 67 MB, in-place state
    float* hv       = (float*)alloc((size_t)N_ATOMS * DD * 4);   // 33.5 MB, in-place state
    float* ebar_i   = (float*)alloc((size_t)N_ATOMS * DD * 4);   // 33.5 MB
    float* node_sum = (float*)alloc((size_t)N_MOLS * DD * 4);
    float* hu0      = (float*)alloc((size_t)N_MOLS * DD * 4);
    float* huA      = (float*)alloc((size_t)N_MOLS * DD * 4);
    float* huB      = (float*)alloc((size_t)N_MOLS * DD * 4);
    float* ebar     = (float*)alloc((size_t)N_MOLS * DD * 4);
    float* vbar     = (float*)alloc((size_t)N_MOLS * DD * 4);

    // ---- init ----
    hipMemsetAsync(node_sum, 0, (size_t)N_MOLS * DD * 4, stream);
    k_init_edges<<<(N_BONDS*DD)/256, 256, 0, stream>>>(bo, Wfe, bfe, he);
    k_init_nodes<<<(N_ATOMS*DD)/256, 256, 0, stream>>>(atoms, Wfv, bfv, hv);
    k_segsum<<<N_ATOMS/128, 128, 0, stream>>>(hv, amol, node_sum, N_ATOMS, 128);
    k_mol_init<<<(N_MOLS*DD)/256, 256, 0, stream>>>(node_sum, Wfu, bfu, hu0);

    const float* hu_in = hu0; float* hu_out = huA;

    for (int r = 0; r < REPEAT; r++) {
        hipMemsetAsync(ebar_i, 0, (size_t)N_ATOMS * DD * 4, stream);
        hipMemsetAsync(ebar,   0, (size_t)N_MOLS * DD * 4, stream);
        hipMemsetAsync(vbar,   0, (size_t)N_MOLS * DD * 4, stream);

        k_phi_e<<<N_BONDS/TE, 256, 0, stream>>>(he, bo, Wfe, bfe, hv, hu_in, We, be,
                                                bsrc, bdst, bmol, ebar_i);
        k_segsum<<<N_BONDS/256, 128, 0, stream>>>(he, bmol, ebar, N_BONDS, 256);
        k_phi_v<<<N_ATOMS/TN, 256, 0, stream>>>(hv, atoms, Wfv, bfv, ebar_i, hu_in,
                                                Wv, bv, amol);
        k_segsum<<<N_ATOMS/256, 128, 0, stream>>>(hv, amol, vbar, N_ATOMS, 256);
        k_phi_u<<<(N_MOLS*DD)/256, 256, 0, stream>>>(hu_in, hu0, ebar, vbar, Wu, bu,
                                                     hu_out, (float*)d_out);

        hu_in = hu_out; hu_out = (hu_out == huA) ? huB : huA;
    }
}

// Round 3
// 1230.654 us; speedup vs baseline: 5.3062x; 5.3062x over previous
//
#include <hip/hip_runtime.h>
#include <hip/hip_bf16.h>
#include <stdint.h>

#define N_ATOMS 65536
#define N_BONDS 131072
#define N_MOLS  512
#define D_IN    16
#define DD      128
#define REPEAT  3
#define PITCH   136   // LDS row pitch in bf16 elems: 272B -> lane-n start bank shifts by 4, 2-way max (free)

typedef __attribute__((ext_vector_type(8))) short s8b;
typedef __attribute__((ext_vector_type(4))) float f32x4;

__device__ __forceinline__ float us2f(unsigned short s) {
    unsigned int u = ((unsigned int)s) << 16;
    float f; __builtin_memcpy(&f, &u, 4); return f;
}
__device__ __forceinline__ unsigned short f2us(float f) {
    __hip_bfloat16 h = __float2bfloat16(f);
    unsigned short s; __builtin_memcpy(&s, &h, 2); return s;
}

// ---------------- one-time prep ----------------

// W[K][N] (fp32) -> WT[N][K] (bf16)
__global__ void k_cast_transpose(const float* __restrict__ W, unsigned short* __restrict__ WT,
                                 int K, int N) {
    int idx = blockIdx.x * 256 + threadIdx.x;
    if (idx >= K * N) return;
    int n = idx / K, k = idx - n * K;
    WT[idx] = f2us(W[k * N + n]);
}

__global__ void k_deg(const int* __restrict__ bsrc, const int* __restrict__ bdst,
                      int* __restrict__ deg) {
    int e = blockIdx.x * 256 + threadIdx.x;
    atomicAdd(&deg[bsrc[e]], 1);
    atomicAdd(&deg[bdst[e]], 1);
}

__global__ void k_scan(const int* __restrict__ deg, int* __restrict__ rowptr,
                       int* __restrict__ cursor) {
    __shared__ int part[1024];
    int t = threadIdx.x;                      // 1024 threads, one block
    int base = t * 64;
    int s = 0;
    for (int i = 0; i < 64; i++) s += deg[base + i];
    part[t] = s;
    __syncthreads();
    if (t == 0) {
        int run = 0;
        for (int i = 0; i < 1024; i++) { int v = part[i]; part[i] = run; run += v; }
    }
    __syncthreads();
    int off = part[t];
    for (int i = 0; i < 64; i++) {
        rowptr[base + i] = off;
        cursor[base + i] = off;
        off += deg[base + i];
    }
    if (t == 1023) rowptr[N_ATOMS] = off;
}

__global__ void k_fill(const int* __restrict__ bsrc, const int* __restrict__ bdst,
                       int* __restrict__ cursor, int* __restrict__ adj) {
    int e = blockIdx.x * 256 + threadIdx.x;
    int p = atomicAdd(&cursor[bsrc[e]], 1); adj[p] = e;
    int q = atomicAdd(&cursor[bdst[e]], 1); adj[q] = e;
}

// ---------------- init ----------------

__global__ void k_init_edges(const float* __restrict__ bo, const float* __restrict__ Wfe,
                             const float* __restrict__ bfe, unsigned short* __restrict__ he) {
    int idx = blockIdx.x * 256 + threadIdx.x;     // E*D
    int e = idx >> 7, d = idx & 127;
    he[idx] = f2us(fmaxf(fmaf(bo[e], Wfe[d], bfe[d]), 0.f));
}

__global__ void k_init_nodes(const float* __restrict__ atoms, const float* __restrict__ Wfv,
                             const float* __restrict__ bfv, unsigned short* __restrict__ hv) {
    int idx = blockIdx.x * 256 + threadIdx.x;     // N*D
    int n = idx >> 7, d = idx & 127;
    float acc = bfv[d];
#pragma unroll
    for (int k = 0; k < D_IN; k++)
        acc = fmaf(atoms[n*D_IN + k], Wfv[k*DD + d], acc);
    hv[idx] = f2us(fmaxf(acc, 0.f));
}

// segment sum of bf16 [rows,128] by sorted ids -> fp32 out (pre-zeroed)
__global__ void k_segsum_bf(const unsigned short* __restrict__ x, const int* __restrict__ ids,
                            float* __restrict__ out, int rows, int chunk) {
    int r0 = blockIdx.x * chunk;
    int d = threadIdx.x;           // 128
    int rend = min(r0 + chunk, rows);
    if (r0 >= rend) return;
    float acc = 0.f;
    int cur = ids[r0];
    for (int r = r0; r < rend; r++) {
        int m = ids[r];
        if (m != cur) { atomicAdd(&out[cur*DD + d], acc); acc = 0.f; cur = m; }
        acc += us2f(x[(size_t)r*DD + d]);
    }
    atomicAdd(&out[cur*DD + d], acc);
}

__global__ void k_mol_init(const float* __restrict__ ns, const float* __restrict__ Wfu,
                           const float* __restrict__ bfu, float* __restrict__ hu0,
                           unsigned short* __restrict__ hub0) {
    int idx = blockIdx.x * 256 + threadIdx.x;    // M*D
    int m = idx >> 7, d = idx & 127;
    float acc = bfu[d];
    for (int k = 0; k < DD; k++)
        acc = fmaf(ns[m*DD + k], Wfu[k*DD + d], acc);
    float v = fmaxf(acc, 0.f);
    hu0[idx] = v;
    hub0[idx] = f2us(v);
}

// ---------------- phi_e (MFMA) ----------------
// he[e] <- relu([h_e | h_e0(recomp) | h_v[src] | h_v[dst] | h_u[mol]] @ W_e + b_e), in place.
// Block: 64 rows x 128 cols, K=640 chunked 5x128. 4 waves; wave w owns cols w*32..w*32+31.
__global__ __launch_bounds__(256) void k_phi_e(
        unsigned short* __restrict__ he,
        const float* __restrict__ bo,  const float* __restrict__ Wfe,
        const float* __restrict__ bfe,
        const unsigned short* __restrict__ hv, const unsigned short* __restrict__ hub,
        const unsigned short* __restrict__ WeT, const float* __restrict__ be,
        const int* __restrict__ bsrc, const int* __restrict__ bdst,
        const int* __restrict__ bmol) {
    __shared__ __align__(16) unsigned short xs[64 * PITCH];
    __shared__ __align__(16) unsigned short wt[128 * PITCH];
    __shared__ int ssrc[64], sdst[64], smol[64];
    __shared__ float sbo[64];
    int tid = threadIdx.x;
    int e0 = blockIdx.x * 64;
    if (tid < 64) {
        ssrc[tid] = bsrc[e0 + tid];
        sdst[tid] = bdst[e0 + tid];
        smol[tid] = bmol[e0 + tid];
        sbo[tid]  = bo[e0 + tid];
    }
    int wv = tid >> 6, lane = tid & 63, quad = lane >> 4, l15 = lane & 15;
    f32x4 acc[4][2];
#pragma unroll
    for (int mt = 0; mt < 4; mt++)
#pragma unroll
        for (int nt = 0; nt < 2; nt++)
            acc[mt][nt] = (f32x4){0.f, 0.f, 0.f, 0.f};
    __syncthreads();

    for (int c = 0; c < 5; c++) {
        // stage X chunk: 64 rows x 128 bf16
        for (int u = tid; u < 64 * 16; u += 256) {
            int i = u >> 4, c8 = (u & 15) * 8;
            uint4 val;
            if (c == 1) {                       // h_e0 recomputed
                unsigned short tmp[8];
#pragma unroll
                for (int j = 0; j < 8; j++)
                    tmp[j] = f2us(fmaxf(fmaf(sbo[i], Wfe[c8 + j], bfe[c8 + j]), 0.f));
                __builtin_memcpy(&val, tmp, 16);
            } else {
                const unsigned short* src;
                if      (c == 0) src = he  + (size_t)(e0 + i) * DD;
                else if (c == 2) src = hv  + (size_t)ssrc[i] * DD;
                else if (c == 3) src = hv  + (size_t)sdst[i] * DD;
                else             src = hub + (size_t)smol[i] * DD;
                val = *reinterpret_cast<const uint4*>(src + c8);
            }
            *reinterpret_cast<uint4*>(&xs[i * PITCH + c8]) = val;
        }
        // stage W chunk: wt[n][kk] = WeT[n][c*128+kk]
        for (int u = tid; u < 128 * 16; u += 256) {
            int n = u >> 4, k8 = (u & 15) * 8;
            uint4 w = *reinterpret_cast<const uint4*>(WeT + (size_t)n * 640 + c * 128 + k8);
            *reinterpret_cast<uint4*>(&wt[n * PITCH + k8]) = w;
        }
        __syncthreads();
#pragma unroll
        for (int ks = 0; ks < 4; ks++) {
            s8b bfr[2], afr[4];
#pragma unroll
            for (int nt = 0; nt < 2; nt++)
                bfr[nt] = *reinterpret_cast<const s8b*>(&wt[(wv*32 + nt*16 + l15) * PITCH + ks*32 + quad*8]);
#pragma unroll
            for (int mt = 0; mt < 4; mt++)
                afr[mt] = *reinterpret_cast<const s8b*>(&xs[(mt*16 + l15) * PITCH + ks*32 + quad*8]);
#pragma unroll
            for (int mt = 0; mt < 4; mt++)
#pragma unroll
                for (int nt = 0; nt < 2; nt++)
                    acc[mt][nt] = __builtin_amdgcn_mfma_f32_16x16x32_bf16(afr[mt], bfr[nt], acc[mt][nt], 0, 0, 0);
        }
        __syncthreads();
    }
    // epilogue: C/D layout col=lane&15, row=quad*4+reg
#pragma unroll
    for (int nt = 0; nt < 2; nt++) {
        int col = wv*32 + nt*16 + l15;
        float bias = be[col];
#pragma unroll
        for (int mt = 0; mt < 4; mt++) {
#pragma unroll
            for (int r = 0; r < 4; r++) {
                int row = e0 + mt*16 + quad*4 + r;
                he[(size_t)row * DD + col] = f2us(fmaxf(acc[mt][nt][r] + bias, 0.f));
            }
        }
    }
}

// ---------------- e_bar_i gather (CSR) ----------------
__global__ __launch_bounds__(256) void k_ebar(const unsigned short* __restrict__ he,
                                              const int* __restrict__ rowptr,
                                              const int* __restrict__ adj,
                                              unsigned short* __restrict__ ebar_i) {
    int n = blockIdx.x * 2 + (threadIdx.x >> 7);
    int d = threadIdx.x & 127;
    int b = rowptr[n], e = rowptr[n + 1];
    float acc = 0.f;
    for (int j = b; j < e; j++)
        acc += us2f(he[(size_t)adj[j] * DD + d]);
    ebar_i[(size_t)n * DD + d] = f2us(acc);
}

// ---------------- phi_v (MFMA) ----------------
// hv[n] <- relu([h_v | h_v0(recomp) | e_bar_i | h_u[amol]] @ W_v + b_v), in place. K=512, 4 chunks.
__global__ __launch_bounds__(256) void k_phi_v(
        unsigned short* __restrict__ hv,
        const float* __restrict__ atoms, const float* __restrict__ Wfv,
        const float* __restrict__ bfv,
        const unsigned short* __restrict__ ebar_i, const unsigned short* __restrict__ hub,
        const unsigned short* __restrict__ WvT, const float* __restrict__ bvv,
        const int* __restrict__ amol) {
    __shared__ __align__(16) unsigned short xs[64 * PITCH];
    __shared__ __align__(16) unsigned short wt[128 * PITCH];
    __shared__ float satoms[64 * D_IN];
    __shared__ int smol[64];
    int tid = threadIdx.x;
    int n0 = blockIdx.x * 64;
    if (tid < 64) smol[tid] = amol[n0 + tid];
    for (int u = tid; u < 64 * D_IN; u += 256) satoms[u] = atoms[(size_t)n0 * D_IN + u];
    int wv = tid >> 6, lane = tid & 63, quad = lane >> 4, l15 = lane & 15;
    f32x4 acc[4][2];
#pragma unroll
    for (int mt = 0; mt < 4; mt++)
#pragma unroll
        for (int nt = 0; nt < 2; nt++)
            acc[mt][nt] = (f32x4){0.f, 0.f, 0.f, 0.f};
    __syncthreads();

    for (int c = 0; c < 4; c++) {
        for (int u = tid; u < 64 * 16; u += 256) {
            int i = u >> 4, c8 = (u & 15) * 8;
            uint4 val;
            if (c == 1) {                       // h_v0 recomputed from atoms
                unsigned short tmp[8];
#pragma unroll
                for (int j = 0; j < 8; j++) {
                    float a = bfv[c8 + j];
#pragma unroll
                    for (int q = 0; q < D_IN; q++)
                        a = fmaf(satoms[i*D_IN + q], Wfv[q*DD + c8 + j], a);
                    tmp[j] = f2us(fmaxf(a, 0.f));
                }
                __builtin_memcpy(&val, tmp, 16);
            } else {
                const unsigned short* src;
                if      (c == 0) src = hv     + (size_t)(n0 + i) * DD;
                else if (c == 2) src = ebar_i + (size_t)(n0 + i) * DD;
                else             src = hub    + (size_t)smol[i] * DD;
                val = *reinterpret_cast<const uint4*>(src + c8);
            }
            *reinterpret_cast<uint4*>(&xs[i * PITCH + c8]) = val;
        }
        for (int u = tid; u < 128 * 16; u += 256) {
            int n = u >> 4, k8 = (u & 15) * 8;
            uint4 w = *reinterpret_cast<const uint4*>(WvT + (size_t)n * 512 + c * 128 + k8);
            *reinterpret_cast<uint4*>(&wt[n * PITCH + k8]) = w;
        }
        __syncthreads();
#pragma unroll
        for (int ks = 0; ks < 4; ks++) {
            s8b bfr[2], afr[4];
#pragma unroll
            for (int nt = 0; nt < 2; nt++)
                bfr[nt] = *reinterpret_cast<const s8b*>(&wt[(wv*32 + nt*16 + l15) * PITCH + ks*32 + quad*8]);
#pragma unroll
            for (int mt = 0; mt < 4; mt++)
                afr[mt] = *reinterpret_cast<const s8b*>(&xs[(mt*16 + l15) * PITCH + ks*32 + quad*8]);
#pragma unroll
            for (int mt = 0; mt < 4; mt++)
#pragma unroll
                for (int nt = 0; nt < 2; nt++)
                    acc[mt][nt] = __builtin_amdgcn_mfma_f32_16x16x32_bf16(afr[mt], bfr[nt], acc[mt][nt], 0, 0, 0);
        }
        __syncthreads();
    }
#pragma unroll
    for (int nt = 0; nt < 2; nt++) {
        int col = wv*32 + nt*16 + l15;
        float bias = bvv[col];
#pragma unroll
        for (int mt = 0; mt < 4; mt++) {
#pragma unroll
            for (int r = 0; r < 4; r++) {
                int row = n0 + mt*16 + quad*4 + r;
                hv[(size_t)row * DD + col] = f2us(fmaxf(acc[mt][nt][r] + bias, 0.f));
            }
        }
    }
}

// ---------------- phi_u ----------------
__global__ void k_phi_u(const float* __restrict__ hu_in, const float* __restrict__ hu0,
                        const float* __restrict__ ebar, const float* __restrict__ vbar,
                        const float* __restrict__ Wu, const float* __restrict__ bu,
                        float* __restrict__ hu_out, unsigned short* __restrict__ hub_out,
                        float* __restrict__ dout) {
    int idx = blockIdx.x * 256 + threadIdx.x;   // M*D
    int m = idx >> 7, d = idx & 127;
    float acc = bu[d];
    const float* segs[4] = { hu_in + m*DD, hu0 + m*DD, ebar + m*DD, vbar + m*DD };
    for (int s = 0; s < 4; s++) {
        const float* x = segs[s];
        const float* W = Wu + (s*DD)*DD + d;
        for (int k = 0; k < DD; k++)
            acc = fmaf(x[k], W[k*DD], acc);
    }
    float v = fmaxf(acc, 0.f);
    hu_out[idx] = v;
    hub_out[idx] = f2us(v);
    dout[idx] = v;
}

// ---------------- launch ----------------

extern "C" void kernel_launch(void* const* d_in, const int* in_sizes, int n_in,
                              void* d_out, int out_size, void* d_ws, size_t ws_size,
                              hipStream_t stream) {
    const float* atoms = (const float*)d_in[0];
    const float* bo    = (const float*)d_in[1];
    const float* Wfe   = (const float*)d_in[2];
    const float* bfe   = (const float*)d_in[3];
    const float* Wfv   = (const float*)d_in[4];
    const float* bfv   = (const float*)d_in[5];
    const float* Wfu   = (const float*)d_in[6];
    const float* bfu   = (const float*)d_in[7];
    const float* We    = (const float*)d_in[8];
    const float* be    = (const float*)d_in[9];
    const float* Wv    = (const float*)d_in[10];
    const float* bv    = (const float*)d_in[11];
    const float* Wu    = (const float*)d_in[12];
    const float* bu    = (const float*)d_in[13];
    const int* bsrc    = (const int*)d_in[14];
    const int* bdst    = (const int*)d_in[15];
    const int* amol    = (const int*)d_in[16];
    const int* bmol    = (const int*)d_in[17];

    char* p = (char*)d_ws;
    auto alloc = [&](size_t bytes) {
        char* r = p;
        p += (bytes + 255) & ~(size_t)255;
        return r;
    };
    unsigned short* he     = (unsigned short*)alloc((size_t)N_BONDS * DD * 2);  // 33.5 MB
    unsigned short* hv     = (unsigned short*)alloc((size_t)N_ATOMS * DD * 2);  // 16.8 MB
    unsigned short* ebar_i = (unsigned short*)alloc((size_t)N_ATOMS * DD * 2);  // 16.8 MB
    unsigned short* WeT    = (unsigned short*)alloc((size_t)DD * 640 * 2);
    unsigned short* WvT    = (unsigned short*)alloc((size_t)DD * 512 * 2);
    int* deg     = (int*)alloc((size_t)N_ATOMS * 4);
    int* rowptr  = (int*)alloc((size_t)(N_ATOMS + 1) * 4);
    int* cursor  = (int*)alloc((size_t)N_ATOMS * 4);
    int* adj     = (int*)alloc((size_t)2 * N_BONDS * 4);
    float* node_sum = (float*)alloc((size_t)N_MOLS * DD * 4);
    float* hu0   = (float*)alloc((size_t)N_MOLS * DD * 4);
    float* huA   = (float*)alloc((size_t)N_MOLS * DD * 4);
    float* huB   = (float*)alloc((size_t)N_MOLS * DD * 4);
    float* ebar  = (float*)alloc((size_t)N_MOLS * DD * 4);
    float* vbar  = (float*)alloc((size_t)N_MOLS * DD * 4);
    unsigned short* hub0 = (unsigned short*)alloc((size_t)N_MOLS * DD * 2);
    unsigned short* hubA = (unsigned short*)alloc((size_t)N_MOLS * DD * 2);
    unsigned short* hubB = (unsigned short*)alloc((size_t)N_MOLS * DD * 2);

    // ---- CSR build (graph is static per launch) ----
    hipMemsetAsync(deg, 0, (size_t)N_ATOMS * 4, stream);
    k_deg<<<N_BONDS/256, 256, 0, stream>>>(bsrc, bdst, deg);
    k_scan<<<1, 1024, 0, stream>>>(deg, rowptr, cursor);
    k_fill<<<N_BONDS/256, 256, 0, stream>>>(bsrc, bdst, cursor, adj);

    // ---- weight prep ----
    k_cast_transpose<<<(640*DD + 255)/256, 256, 0, stream>>>(We, WeT, 640, DD);
    k_cast_transpose<<<(512*DD + 255)/256, 256, 0, stream>>>(Wv, WvT, 512, DD);

    // ---- init ----
    k_init_edges<<<(N_BONDS*DD)/256, 256, 0, stream>>>(bo, Wfe, bfe, he);
    k_init_nodes<<<(N_ATOMS*DD)/256, 256, 0, stream>>>(atoms, Wfv, bfv, hv);
    hipMemsetAsync(node_sum, 0, (size_t)N_MOLS * DD * 4, stream);
    k_segsum_bf<<<N_ATOMS/128, 128, 0, stream>>>(hv, amol, node_sum, N_ATOMS, 128);
    k_mol_init<<<(N_MOLS*DD)/256, 256, 0, stream>>>(node_sum, Wfu, bfu, hu0, hub0);

    const float* hu_in = hu0; float* hu_out = huA;
    const unsigned short* hub_in = hub0; unsigned short* hub_out = hubA;

    for (int r = 0; r < REPEAT; r++) {
        hipMemsetAsync(ebar, 0, (size_t)N_MOLS * DD * 4, stream);
        hipMemsetAsync(vbar, 0, (size_t)N_MOLS * DD * 4, stream);

        k_phi_e<<<N_BONDS/64, 256, 0, stream>>>(he, bo, Wfe, bfe, hv, hub_in, WeT, be,
                                                bsrc, bdst, bmol);
        k_ebar<<<N_ATOMS/2, 256, 0, stream>>>(he, rowptr, adj, ebar_i);
        k_segsum_bf<<<N_BONDS/256, 128, 0, stream>>>(he, bmol, ebar, N_BONDS, 256);
        k_phi_v<<<N_ATOMS/64, 256, 0, stream>>>(hv, atoms, Wfv, bfv, ebar_i, hub_in,
                                                WvT, bv, amol);
        k_segsum_bf<<<N_ATOMS/256, 128, 0, stream>>>(hv, amol, vbar, N_ATOMS, 256);
        k_phi_u<<<(N_MOLS*DD)/256, 256, 0, stream>>>(hu_in, hu0, ebar, vbar, Wu, bu,
                                                     hu_out, hub_out, (float*)d_out);

        hu_in = hu_out;  hu_out  = (hu_out  == huA)  ? huB  : huA;
        hub_in = hub_out; hub_out = (hub_out == hubA) ? hubB : hubA;
    }
}

// Round 4
// 853.748 us; speedup vs baseline: 7.6488x; 1.4415x over previous
//
#include <hip/hip_runtime.h>
#include <hip/hip_bf16.h>
#include <stdint.h>

#define N_ATOMS 65536
#define N_BONDS 131072
#define N_MOLS  512
#define D_IN    16
#define DD      128
#define REPEAT  3
#define PITCH   136   // LDS row pitch (bf16): 272 B -> row-to-row bank shift of 4, 2-way max (free)

typedef __attribute__((ext_vector_type(8))) short s8b;
typedef __attribute__((ext_vector_type(4))) float f32x4;

__device__ __forceinline__ float us2f(unsigned short s) {
    unsigned int u = ((unsigned int)s) << 16;
    float f; __builtin_memcpy(&f, &u, 4); return f;
}
__device__ __forceinline__ unsigned short f2us(float f) {
    __hip_bfloat16 h = __float2bfloat16(f);
    unsigned short s; __builtin_memcpy(&s, &h, 2); return s;
}

// ---------------- one-time prep ----------------

// Pack W[K][128] fp32 -> bf16 fragment order: Wpk[((c*4+ks)*4+quad)*128 + n][8]
// where k = c*128 + ks*32 + quad*8 + j. B-frag load for (c,ks,quad,col) is then
// 16 B at ((c*4+ks)*4+quad)*1024 + col*8 -> 16 consecutive cols = 256 B contiguous.
__global__ void k_pack_w(const float* __restrict__ W, unsigned short* __restrict__ Wpk, int K) {
    int idx = blockIdx.x * 256 + threadIdx.x;     // K*128
    if (idx >= K * 128) return;
    int k = idx >> 7, n = idx & 127;
    int c = k >> 7, ks = (k >> 5) & 3, quad = (k >> 3) & 3, j = k & 7;
    int pidx = (((c * 4 + ks) * 4 + quad) * 128 + n) * 8 + j;
    Wpk[pidx] = f2us(W[k * 128 + n]);
}

__global__ void k_deg(const int* __restrict__ bsrc, const int* __restrict__ bdst,
                      int* __restrict__ deg) {
    int e = blockIdx.x * 256 + threadIdx.x;
    atomicAdd(&deg[bsrc[e]], 1);
    atomicAdd(&deg[bdst[e]], 1);
}

__global__ void k_scan(const int* __restrict__ deg, int* __restrict__ rowptr,
                       int* __restrict__ cursor) {
    __shared__ int part[1024];
    int t = threadIdx.x;                      // 1024 threads, one block
    int base = t * 64;
    int s = 0;
    for (int i = 0; i < 64; i++) s += deg[base + i];
    part[t] = s;
    __syncthreads();
    if (t == 0) {
        int run = 0;
        for (int i = 0; i < 1024; i++) { int v = part[i]; part[i] = run; run += v; }
    }
    __syncthreads();
    int off = part[t];
    for (int i = 0; i < 64; i++) {
        rowptr[base + i] = off;
        cursor[base + i] = off;
        off += deg[base + i];
    }
    if (t == 1023) rowptr[N_ATOMS] = off;
}

__global__ void k_fill(const int* __restrict__ bsrc, const int* __restrict__ bdst,
                       int* __restrict__ cursor, int* __restrict__ adj) {
    int e = blockIdx.x * 256 + threadIdx.x;
    int p = atomicAdd(&cursor[bsrc[e]], 1); adj[p] = e;
    int q = atomicAdd(&cursor[bdst[e]], 1); adj[q] = e;
}

// ---------------- init ----------------

__global__ void k_init_edges(const float* __restrict__ bo, const float* __restrict__ Wfe,
                             const float* __restrict__ bfe,
                             unsigned short* __restrict__ he, unsigned short* __restrict__ he0) {
    int idx = blockIdx.x * 256 + threadIdx.x;     // E*D
    int e = idx >> 7, d = idx & 127;
    unsigned short v = f2us(fmaxf(fmaf(bo[e], Wfe[d], bfe[d]), 0.f));
    he[idx] = v; he0[idx] = v;
}

__global__ void k_init_nodes(const float* __restrict__ atoms, const float* __restrict__ Wfv,
                             const float* __restrict__ bfv,
                             unsigned short* __restrict__ hv, unsigned short* __restrict__ hv0) {
    int idx = blockIdx.x * 256 + threadIdx.x;     // N*D
    int n = idx >> 7, d = idx & 127;
    float acc = bfv[d];
#pragma unroll
    for (int k = 0; k < D_IN; k++)
        acc = fmaf(atoms[n*D_IN + k], Wfv[k*DD + d], acc);
    unsigned short v = f2us(fmaxf(acc, 0.f));
    hv[idx] = v; hv0[idx] = v;
}

// segment sum of bf16 [rows,128] by sorted ids -> fp32 out (pre-zeroed).
// 256 threads = 2 rows x 128 cols per iteration; run-length accumulate, flush at id change.
__global__ __launch_bounds__(256) void k_segsum2(const unsigned short* __restrict__ x,
                                                 const int* __restrict__ ids,
                                                 float* __restrict__ out, int rpb) {
    int r0 = blockIdx.x * rpb;
    int d = threadIdx.x & 127;
    int half = threadIdx.x >> 7;
    float acc = 0.f;
    int cur = ids[r0 + half];
    for (int r = r0 + half; r < r0 + rpb; r += 2) {
        int m = ids[r];
        if (m != cur) { atomicAdd(&out[cur*DD + d], acc); acc = 0.f; cur = m; }
        acc += us2f(x[(size_t)r*DD + d]);
    }
    atomicAdd(&out[cur*DD + d], acc);
}

__global__ void k_mol_init(const float* __restrict__ ns, const float* __restrict__ Wfu,
                           const float* __restrict__ bfu, float* __restrict__ hu0,
                           unsigned short* __restrict__ hub0) {
    int idx = blockIdx.x * 256 + threadIdx.x;    // M*D
    int m = idx >> 7, d = idx & 127;
    float acc = bfu[d];
    for (int k = 0; k < DD; k++)
        acc = fmaf(ns[m*DD + k], Wfu[k*DD + d], acc);
    float v = fmaxf(acc, 0.f);
    hu0[idx] = v;
    hub0[idx] = f2us(v);
}

// ---------------- phi_e (MFMA, 128 rows x 128 cols per block) ----------------
// he[e] <- relu([h_e | h_e0 | h_v[src] | h_v[dst] | h_u[mol]] @ W_e + b_e), in place.
// X chunks staged in LDS; B-fragments read directly from packed global W (L2-resident).
__global__ __launch_bounds__(256) void k_phi_e(
        unsigned short* __restrict__ he, const unsigned short* __restrict__ he0,
        const unsigned short* __restrict__ hv, const unsigned short* __restrict__ hub,
        const unsigned short* __restrict__ Wpk, const float* __restrict__ be,
        const int* __restrict__ bsrc, const int* __restrict__ bdst,
        const int* __restrict__ bmol) {
    __shared__ __align__(16) unsigned short xs[128 * PITCH];
    __shared__ int ssrc[128], sdst[128], smol[128];
    int tid = threadIdx.x;
    int e0 = blockIdx.x * 128;
    if (tid < 128) {
        ssrc[tid] = bsrc[e0 + tid];
        sdst[tid] = bdst[e0 + tid];
        smol[tid] = bmol[e0 + tid];
    }
    int wv = tid >> 6, lane = tid & 63, quad = lane >> 4, l15 = lane & 15;
    f32x4 acc[8][2];
#pragma unroll
    for (int mt = 0; mt < 8; mt++)
#pragma unroll
        for (int nt = 0; nt < 2; nt++)
            acc[mt][nt] = (f32x4){0.f, 0.f, 0.f, 0.f};
    __syncthreads();

    for (int c = 0; c < 5; c++) {
        // stage X chunk: 128 rows x 128 bf16 (uniform row copies)
        for (int u = tid; u < 128 * 16; u += 256) {
            int i = u >> 4, c8 = (u & 15) * 8;
            const unsigned short* src;
            if      (c == 0) src = he  + (size_t)(e0 + i) * DD;
            else if (c == 1) src = he0 + (size_t)(e0 + i) * DD;
            else if (c == 2) src = hv  + (size_t)ssrc[i] * DD;
            else if (c == 3) src = hv  + (size_t)sdst[i] * DD;
            else             src = hub + (size_t)smol[i] * DD;
            *reinterpret_cast<uint4*>(&xs[i * PITCH + c8]) =
                *reinterpret_cast<const uint4*>(src + c8);
        }
        __syncthreads();
#pragma unroll
        for (int ks = 0; ks < 4; ks++) {
            const unsigned short* wb = Wpk + ((c * 4 + ks) * 4 + quad) * 1024;
            s8b bfr[2];
#pragma unroll
            for (int nt = 0; nt < 2; nt++)
                bfr[nt] = *reinterpret_cast<const s8b*>(wb + (wv*32 + nt*16 + l15) * 8);
#pragma unroll
            for (int mt = 0; mt < 8; mt++) {
                s8b afr = *reinterpret_cast<const s8b*>(&xs[(mt*16 + l15) * PITCH + ks*32 + quad*8]);
#pragma unroll
                for (int nt = 0; nt < 2; nt++)
                    acc[mt][nt] = __builtin_amdgcn_mfma_f32_16x16x32_bf16(afr, bfr[nt], acc[mt][nt], 0, 0, 0);
            }
        }
        __syncthreads();
    }
    // epilogue: C/D layout col=lane&15, row=quad*4+reg
#pragma unroll
    for (int nt = 0; nt < 2; nt++) {
        int col = wv*32 + nt*16 + l15;
        float bias = be[col];
#pragma unroll
        for (int mt = 0; mt < 8; mt++)
#pragma unroll
            for (int r = 0; r < 4; r++) {
                int row = e0 + mt*16 + quad*4 + r;
                he[(size_t)row * DD + col] = f2us(fmaxf(acc[mt][nt][r] + bias, 0.f));
            }
    }
}

// ---------------- e_bar_i gather (CSR) ----------------
__global__ __launch_bounds__(256) void k_ebar(const unsigned short* __restrict__ he,
                                              const int* __restrict__ rowptr,
                                              const int* __restrict__ adj,
                                              unsigned short* __restrict__ ebar_i) {
    int n = blockIdx.x * 2 + (threadIdx.x >> 7);
    int d = threadIdx.x & 127;
    int b = rowptr[n], e = rowptr[n + 1];
    float acc = 0.f;
    for (int j = b; j < e; j++)
        acc += us2f(he[(size_t)adj[j] * DD + d]);
    ebar_i[(size_t)n * DD + d] = f2us(acc);
}

// ---------------- phi_v (MFMA, 128x128 per block) ----------------
__global__ __launch_bounds__(256) void k_phi_v(
        unsigned short* __restrict__ hv, const unsigned short* __restrict__ hv0,
        const unsigned short* __restrict__ ebar_i, const unsigned short* __restrict__ hub,
        const unsigned short* __restrict__ Wpk, const float* __restrict__ bvv,
        const int* __restrict__ amol) {
    __shared__ __align__(16) unsigned short xs[128 * PITCH];
    __shared__ int smol[128];
    int tid = threadIdx.x;
    int n0 = blockIdx.x * 128;
    if (tid < 128) smol[tid] = amol[n0 + tid];
    int wv = tid >> 6, lane = tid & 63, quad = lane >> 4, l15 = lane & 15;
    f32x4 acc[8][2];
#pragma unroll
    for (int mt = 0; mt < 8; mt++)
#pragma unroll
        for (int nt = 0; nt < 2; nt++)
            acc[mt][nt] = (f32x4){0.f, 0.f, 0.f, 0.f};
    __syncthreads();

    for (int c = 0; c < 4; c++) {
        for (int u = tid; u < 128 * 16; u += 256) {
            int i = u >> 4, c8 = (u & 15) * 8;
            const unsigned short* src;
            if      (c == 0) src = hv     + (size_t)(n0 + i) * DD;
            else if (c == 1) src = hv0    + (size_t)(n0 + i) * DD;
            else if (c == 2) src = ebar_i + (size_t)(n0 + i) * DD;
            else             src = hub    + (size_t)smol[i] * DD;
            *reinterpret_cast<uint4*>(&xs[i * PITCH + c8]) =
                *reinterpret_cast<const uint4*>(src + c8);
        }
        __syncthreads();
#pragma unroll
        for (int ks = 0; ks < 4; ks++) {
            const unsigned short* wb = Wpk + ((c * 4 + ks) * 4 + quad) * 1024;
            s8b bfr[2];
#pragma unroll
            for (int nt = 0; nt < 2; nt++)
                bfr[nt] = *reinterpret_cast<const s8b*>(wb + (wv*32 + nt*16 + l15) * 8);
#pragma unroll
            for (int mt = 0; mt < 8; mt++) {
                s8b afr = *reinterpret_cast<const s8b*>(&xs[(mt*16 + l15) * PITCH + ks*32 + quad*8]);
#pragma unroll
                for (int nt = 0; nt < 2; nt++)
                    acc[mt][nt] = __builtin_amdgcn_mfma_f32_16x16x32_bf16(afr, bfr[nt], acc[mt][nt], 0, 0, 0);
            }
        }
        __syncthreads();
    }
#pragma unroll
    for (int nt = 0; nt < 2; nt++) {
        int col = wv*32 + nt*16 + l15;
        float bias = bvv[col];
#pragma unroll
        for (int mt = 0; mt < 8; mt++)
#pragma unroll
            for (int r = 0; r < 4; r++) {
                int row = n0 + mt*16 + quad*4 + r;
                hv[(size_t)row * DD + col] = f2us(fmaxf(acc[mt][nt][r] + bias, 0.f));
            }
    }
}

// ---------------- phi_u ----------------
__global__ void k_phi_u(const float* __restrict__ hu_in, const float* __restrict__ hu0,
                        const float* __restrict__ ebar, const float* __restrict__ vbar,
                        const float* __restrict__ Wu, const float* __restrict__ bu,
                        float* __restrict__ hu_out, unsigned short* __restrict__ hub_out,
                        float* __restrict__ dout) {
    int idx = blockIdx.x * 256 + threadIdx.x;   // M*D
    int m = idx >> 7, d = idx & 127;
    float acc = bu[d];
    const float* segs[4] = { hu_in + m*DD, hu0 + m*DD, ebar + m*DD, vbar + m*DD };
    for (int s = 0; s < 4; s++) {
        const float* x = segs[s];
        const float* W = Wu + (s*DD)*DD + d;
        for (int k = 0; k < DD; k++)
            acc = fmaf(x[k], W[k*DD], acc);
    }
    float v = fmaxf(acc, 0.f);
    hu_out[idx] = v;
    hub_out[idx] = f2us(v);
    dout[idx] = v;
}

// ---------------- launch ----------------

extern "C" void kernel_launch(void* const* d_in, const int* in_sizes, int n_in,
                              void* d_out, int out_size, void* d_ws, size_t ws_size,
                              hipStream_t stream) {
    const float* atoms = (const float*)d_in[0];
    const float* bo    = (const float*)d_in[1];
    const float* Wfe   = (const float*)d_in[2];
    const float* bfe   = (const float*)d_in[3];
    const float* Wfv   = (const float*)d_in[4];
    const float* bfv   = (const float*)d_in[5];
    const float* Wfu   = (const float*)d_in[6];
    const float* bfu   = (const float*)d_in[7];
    const float* We    = (const float*)d_in[8];
    const float* be    = (const float*)d_in[9];
    const float* Wv    = (const float*)d_in[10];
    const float* bv    = (const float*)d_in[11];
    const float* Wu    = (const float*)d_in[12];
    const float* bu    = (const float*)d_in[13];
    const int* bsrc    = (const int*)d_in[14];
    const int* bdst    = (const int*)d_in[15];
    const int* amol    = (const int*)d_in[16];
    const int* bmol    = (const int*)d_in[17];

    char* p = (char*)d_ws;
    auto alloc = [&](size_t bytes) {
        char* r = p;
        p += (bytes + 255) & ~(size_t)255;
        return r;
    };
    unsigned short* he     = (unsigned short*)alloc((size_t)N_BONDS * DD * 2);
    unsigned short* he0b   = (unsigned short*)alloc((size_t)N_BONDS * DD * 2);
    unsigned short* hv     = (unsigned short*)alloc((size_t)N_ATOMS * DD * 2);
    unsigned short* hv0b   = (unsigned short*)alloc((size_t)N_ATOMS * DD * 2);
    unsigned short* ebar_i = (unsigned short*)alloc((size_t)N_ATOMS * DD * 2);
    unsigned short* WeP    = (unsigned short*)alloc((size_t)640 * DD * 2);
    unsigned short* WvP    = (unsigned short*)alloc((size_t)512 * DD * 2);
    int* deg     = (int*)alloc((size_t)N_ATOMS * 4);
    int* rowptr  = (int*)alloc((size_t)(N_ATOMS + 1) * 4);
    int* cursor  = (int*)alloc((size_t)N_ATOMS * 4);
    int* adj     = (int*)alloc((size_t)2 * N_BONDS * 4);
    float* node_sum = (float*)alloc((size_t)N_MOLS * DD * 4);
    float* hu0   = (float*)alloc((size_t)N_MOLS * DD * 4);
    float* huA   = (float*)alloc((size_t)N_MOLS * DD * 4);
    float* huB   = (float*)alloc((size_t)N_MOLS * DD * 4);
    float* ebar  = (float*)alloc((size_t)N_MOLS * DD * 4);
    float* vbar  = (float*)alloc((size_t)N_MOLS * DD * 4);
    unsigned short* hub0 = (unsigned short*)alloc((size_t)N_MOLS * DD * 2);
    unsigned short* hubA = (unsigned short*)alloc((size_t)N_MOLS * DD * 2);
    unsigned short* hubB = (unsigned short*)alloc((size_t)N_MOLS * DD * 2);

    // ---- CSR build ----
    hipMemsetAsync(deg, 0, (size_t)N_ATOMS * 4, stream);
    k_deg<<<N_BONDS/256, 256, 0, stream>>>(bsrc, bdst, deg);
    k_scan<<<1, 1024, 0, stream>>>(deg, rowptr, cursor);
    k_fill<<<N_BONDS/256, 256, 0, stream>>>(bsrc, bdst, cursor, adj);

    // ---- weight packing ----
    k_pack_w<<<(640*DD)/256, 256, 0, stream>>>(We, WeP, 640);
    k_pack_w<<<(512*DD)/256, 256, 0, stream>>>(Wv, WvP, 512);

    // ---- init ----
    k_init_edges<<<(N_BONDS*DD)/256, 256, 0, stream>>>(bo, Wfe, bfe, he, he0b);
    k_init_nodes<<<(N_ATOMS*DD)/256, 256, 0, stream>>>(atoms, Wfv, bfv, hv, hv0b);
    hipMemsetAsync(node_sum, 0, (size_t)N_MOLS * DD * 4, stream);
    k_segsum2<<<N_ATOMS/128, 256, 0, stream>>>(hv, amol, node_sum, 128);
    k_mol_init<<<(N_MOLS*DD)/256, 256, 0, stream>>>(node_sum, Wfu, bfu, hu0, hub0);

    const float* hu_in = hu0; float* hu_out = huA;
    const unsigned short* hub_in = hub0; unsigned short* hub_out = hubA;

    for (int r = 0; r < REPEAT; r++) {
        hipMemsetAsync(ebar, 0, (size_t)N_MOLS * DD * 4, stream);
        hipMemsetAsync(vbar, 0, (size_t)N_MOLS * DD * 4, stream);

        k_phi_e<<<N_BONDS/128, 256, 0, stream>>>(he, he0b, hv, hub_in, WeP, be,
                                                 bsrc, bdst, bmol);
        k_ebar<<<N_ATOMS/2, 256, 0, stream>>>(he, rowptr, adj, ebar_i);
        k_segsum2<<<N_BONDS/128, 256, 0, stream>>>(he, bmol, ebar, 128);
        k_phi_v<<<N_ATOMS/128, 256, 0, stream>>>(hv, hv0b, ebar_i, hub_in, WvP, bv, amol);
        k_segsum2<<<N_ATOMS/128, 256, 0, stream>>>(hv, amol, vbar, 128);
        k_phi_u<<<(N_MOLS*DD)/256, 256, 0, stream>>>(hu_in, hu0, ebar, vbar, Wu, bu,
                                                     hu_out, hub_out, (float*)d_out);

        hu_in = hu_out;  hu_out  = (hu_out  == huA)  ? huB  : huA;
        hub_in = hub_out; hub_out = (hub_out == hubA) ? hubB : hubA;
    }
}

// Round 5
// 604.783 us; speedup vs baseline: 10.7975x; 1.4117x over previous
//
#include <hip/hip_runtime.h>
#include <hip/hip_bf16.h>
#include <stdint.h>

#define N_ATOMS 65536
#define N_BONDS 131072
#define N_MOLS  512
#define D_IN    16
#define DD      128
#define REPEAT  3
#define PITCH   136   // LDS row pitch (bf16): 272 B -> row-to-row bank shift of 4, 2-way max (free)

typedef __attribute__((ext_vector_type(8))) short s8b;
typedef __attribute__((ext_vector_type(4))) float f32x4;

__device__ __forceinline__ float us2f(unsigned short s) {
    unsigned int u = ((unsigned int)s) << 16;
    float f; __builtin_memcpy(&f, &u, 4); return f;
}
__device__ __forceinline__ unsigned short f2us(float f) {
    __hip_bfloat16 h = __float2bfloat16(f);
    unsigned short s; __builtin_memcpy(&s, &h, 2); return s;
}
__device__ __forceinline__ void acc8(float* a, uint4 v) {
    unsigned short w[8]; __builtin_memcpy(w, &v, 16);
#pragma unroll
    for (int j = 0; j < 8; j++) a[j] += us2f(w[j]);
}

// ---------------- one-time prep ----------------

// Pack W[K][128] fp32 -> bf16 fragment order: Wpk[((c*4+ks)*4+quad)*128 + n][8]
__global__ void k_pack_w(const float* __restrict__ W, unsigned short* __restrict__ Wpk, int K) {
    int idx = blockIdx.x * 256 + threadIdx.x;     // K*128
    if (idx >= K * 128) return;
    int k = idx >> 7, n = idx & 127;
    int c = k >> 7, ks = (k >> 5) & 3, quad = (k >> 3) & 3, j = k & 7;
    int pidx = (((c * 4 + ks) * 4 + quad) * 128 + n) * 8 + j;
    Wpk[pidx] = f2us(W[k * 128 + n]);
}

__global__ void k_deg(const int* __restrict__ bsrc, const int* __restrict__ bdst,
                      int* __restrict__ deg) {
    int e = blockIdx.x * 256 + threadIdx.x;
    atomicAdd(&deg[bsrc[e]], 1);
    atomicAdd(&deg[bdst[e]], 1);
}

__global__ void k_scan(const int* __restrict__ deg, int* __restrict__ rowptr,
                       int* __restrict__ cursor) {
    __shared__ int part[1024];
    int t = threadIdx.x;                      // 1024 threads, one block
    int base = t * 64;
    int s = 0;
    for (int i = 0; i < 64; i++) s += deg[base + i];
    part[t] = s;
    __syncthreads();
    if (t == 0) {
        int run = 0;
        for (int i = 0; i < 1024; i++) { int v = part[i]; part[i] = run; run += v; }
    }
    __syncthreads();
    int off = part[t];
    for (int i = 0; i < 64; i++) {
        rowptr[base + i] = off;
        cursor[base + i] = off;
        off += deg[base + i];
    }
    if (t == 1023) rowptr[N_ATOMS] = off;
}

__global__ void k_fill(const int* __restrict__ bsrc, const int* __restrict__ bdst,
                       int* __restrict__ cursor, int* __restrict__ adj) {
    int e = blockIdx.x * 256 + threadIdx.x;
    int p = atomicAdd(&cursor[bsrc[e]], 1); adj[p] = e;
    int q = atomicAdd(&cursor[bdst[e]], 1); adj[q] = e;
}

// mol_ptr[m] = lower_bound(ids, m) for sorted ids; one block of >=513 threads
__global__ void k_molptr(const int* __restrict__ ids, int rows, int* __restrict__ mptr) {
    int m = threadIdx.x;                      // 0..512
    if (m > N_MOLS) return;
    int lo = 0, hi = rows;
    while (lo < hi) {
        int mid = (lo + hi) >> 1;
        if (ids[mid] < m) lo = mid + 1; else hi = mid;
    }
    mptr[m] = lo;
}

// ---------------- init ----------------

__global__ void k_init_edges(const float* __restrict__ bo, const float* __restrict__ Wfe,
                             const float* __restrict__ bfe,
                             unsigned short* __restrict__ he, unsigned short* __restrict__ he0) {
    int idx = blockIdx.x * 256 + threadIdx.x;     // E*D
    int e = idx >> 7, d = idx & 127;
    unsigned short v = f2us(fmaxf(fmaf(bo[e], Wfe[d], bfe[d]), 0.f));
    he[idx] = v; he0[idx] = v;
}

__global__ void k_init_nodes(const float* __restrict__ atoms, const float* __restrict__ Wfv,
                             const float* __restrict__ bfv,
                             unsigned short* __restrict__ hv, unsigned short* __restrict__ hv0) {
    int idx = blockIdx.x * 256 + threadIdx.x;     // N*D
    int n = idx >> 7, d = idx & 127;
    float acc = bfv[d];
#pragma unroll
    for (int k = 0; k < D_IN; k++)
        acc = fmaf(atoms[n*D_IN + k], Wfv[k*DD + d], acc);
    unsigned short v = f2us(fmaxf(acc, 0.f));
    hv[idx] = v; hv0[idx] = v;
}

// per-molecule sum of bf16 [rows,128] over contiguous range mptr[m]..mptr[m+1] -> fp32 out[M][128]
// 256 threads: 16 row-lanes x 16 col-groups (uint4); LDS cross-lane reduce; no atomics.
__global__ __launch_bounds__(256) void k_molsum(const unsigned short* __restrict__ x,
                                                const int* __restrict__ mptr,
                                                float* __restrict__ out) {
    __shared__ float red[16 * 128];
    int m = blockIdx.x;
    int b = mptr[m], e = mptr[m + 1];
    int rl = threadIdx.x >> 4, g = threadIdx.x & 15;
    float acc[8] = {0,0,0,0,0,0,0,0};
    for (int r = b + rl; r < e; r += 16) {
        uint4 v = *reinterpret_cast<const uint4*>(x + (size_t)r * DD + g * 8);
        acc8(acc, v);
    }
#pragma unroll
    for (int j = 0; j < 8; j++) red[rl * 128 + g * 8 + j] = acc[j];
    __syncthreads();
    if (threadIdx.x < 128) {
        int col = threadIdx.x;
        float s = 0.f;
#pragma unroll
        for (int i = 0; i < 16; i++) s += red[i * 128 + col];
        out[(size_t)m * DD + col] = s;
    }
}

__global__ void k_mol_init(const float* __restrict__ ns, const float* __restrict__ Wfu,
                           const float* __restrict__ bfu, float* __restrict__ hu0,
                           unsigned short* __restrict__ hub0) {
    int idx = blockIdx.x * 256 + threadIdx.x;    // M*D
    int m = idx >> 7, d = idx & 127;
    float acc = bfu[d];
    for (int k = 0; k < DD; k++)
        acc = fmaf(ns[m*DD + k], Wfu[k*DD + d], acc);
    float v = fmaxf(acc, 0.f);
    hu0[idx] = v;
    hub0[idx] = f2us(v);
}

// ---------------- phi_e (MFMA, 128 rows x 128 cols per block) ----------------
__global__ __launch_bounds__(256) void k_phi_e(
        unsigned short* __restrict__ he, const unsigned short* __restrict__ he0,
        const unsigned short* __restrict__ hv, const unsigned short* __restrict__ hub,
        const unsigned short* __restrict__ Wpk, const float* __restrict__ be,
        const int* __restrict__ bsrc, const int* __restrict__ bdst,
        const int* __restrict__ bmol) {
    __shared__ __align__(16) unsigned short xs[128 * PITCH];
    __shared__ int ssrc[128], sdst[128], smol[128];
    int tid = threadIdx.x;
    int e0 = blockIdx.x * 128;
    if (tid < 128) {
        ssrc[tid] = bsrc[e0 + tid];
        sdst[tid] = bdst[e0 + tid];
        smol[tid] = bmol[e0 + tid];
    }
    int wv = tid >> 6, lane = tid & 63, quad = lane >> 4, l15 = lane & 15;
    f32x4 acc[8][2];
#pragma unroll
    for (int mt = 0; mt < 8; mt++)
#pragma unroll
        for (int nt = 0; nt < 2; nt++)
            acc[mt][nt] = (f32x4){0.f, 0.f, 0.f, 0.f};
    __syncthreads();

    for (int c = 0; c < 5; c++) {
        for (int u = tid; u < 128 * 16; u += 256) {
            int i = u >> 4, c8 = (u & 15) * 8;
            const unsigned short* src;
            if      (c == 0) src = he  + (size_t)(e0 + i) * DD;
            else if (c == 1) src = he0 + (size_t)(e0 + i) * DD;
            else if (c == 2) src = hv  + (size_t)ssrc[i] * DD;
            else if (c == 3) src = hv  + (size_t)sdst[i] * DD;
            else             src = hub + (size_t)smol[i] * DD;
            *reinterpret_cast<uint4*>(&xs[i * PITCH + c8]) =
                *reinterpret_cast<const uint4*>(src + c8);
        }
        __syncthreads();
#pragma unroll
        for (int ks = 0; ks < 4; ks++) {
            const unsigned short* wb = Wpk + ((c * 4 + ks) * 4 + quad) * 1024;
            s8b bfr[2];
#pragma unroll
            for (int nt = 0; nt < 2; nt++)
                bfr[nt] = *reinterpret_cast<const s8b*>(wb + (wv*32 + nt*16 + l15) * 8);
#pragma unroll
            for (int mt = 0; mt < 8; mt++) {
                s8b afr = *reinterpret_cast<const s8b*>(&xs[(mt*16 + l15) * PITCH + ks*32 + quad*8]);
#pragma unroll
                for (int nt = 0; nt < 2; nt++)
                    acc[mt][nt] = __builtin_amdgcn_mfma_f32_16x16x32_bf16(afr, bfr[nt], acc[mt][nt], 0, 0, 0);
            }
        }
        __syncthreads();
    }
#pragma unroll
    for (int nt = 0; nt < 2; nt++) {
        int col = wv*32 + nt*16 + l15;
        float bias = be[col];
#pragma unroll
        for (int mt = 0; mt < 8; mt++)
#pragma unroll
            for (int r = 0; r < 4; r++) {
                int row = e0 + mt*16 + quad*4 + r;
                he[(size_t)row * DD + col] = f2us(fmaxf(acc[mt][nt][r] + bias, 0.f));
            }
    }
}

// ---------------- e_bar_i gather (CSR, vectorized) ----------------
// 16 atoms/block; 16 threads per atom, each owning 8 cols (uint4 per edge row).
__global__ __launch_bounds__(256) void k_ebar(const unsigned short* __restrict__ he,
                                              const int* __restrict__ rowptr,
                                              const int* __restrict__ adj,
                                              unsigned short* __restrict__ ebar_i) {
    int n = blockIdx.x * 16 + (threadIdx.x >> 4);
    int g = threadIdx.x & 15;
    int b = rowptr[n], e = rowptr[n + 1];
    float acc[8] = {0,0,0,0,0,0,0,0};
    int j = b;
    for (; j + 1 < e; j += 2) {
        int e0i = adj[j], e1i = adj[j + 1];
        uint4 v0 = *reinterpret_cast<const uint4*>(he + (size_t)e0i * DD + g * 8);
        uint4 v1 = *reinterpret_cast<const uint4*>(he + (size_t)e1i * DD + g * 8);
        acc8(acc, v0);
        acc8(acc, v1);
    }
    if (j < e) {
        uint4 v0 = *reinterpret_cast<const uint4*>(he + (size_t)adj[j] * DD + g * 8);
        acc8(acc, v0);
    }
    unsigned short o[8];
#pragma unroll
    for (int k = 0; k < 8; k++) o[k] = f2us(acc[k]);
    uint4 ov; __builtin_memcpy(&ov, o, 16);
    *reinterpret_cast<uint4*>(ebar_i + (size_t)n * DD + g * 8) = ov;
}

// ---------------- phi_v (MFMA, 128x128 per block) ----------------
__global__ __launch_bounds__(256) void k_phi_v(
        unsigned short* __restrict__ hv, const unsigned short* __restrict__ hv0,
        const unsigned short* __restrict__ ebar_i, const unsigned short* __restrict__ hub,
        const unsigned short* __restrict__ Wpk, const float* __restrict__ bvv,
        const int* __restrict__ amol) {
    __shared__ __align__(16) unsigned short xs[128 * PITCH];
    __shared__ int smol[128];
    int tid = threadIdx.x;
    int n0 = blockIdx.x * 128;
    if (tid < 128) smol[tid] = amol[n0 + tid];
    int wv = tid >> 6, lane = tid & 63, quad = lane >> 4, l15 = lane & 15;
    f32x4 acc[8][2];
#pragma unroll
    for (int mt = 0; mt < 8; mt++)
#pragma unroll
        for (int nt = 0; nt < 2; nt++)
            acc[mt][nt] = (f32x4){0.f, 0.f, 0.f, 0.f};
    __syncthreads();

    for (int c = 0; c < 4; c++) {
        for (int u = tid; u < 128 * 16; u += 256) {
            int i = u >> 4, c8 = (u & 15) * 8;
            const unsigned short* src;
            if      (c == 0) src = hv     + (size_t)(n0 + i) * DD;
            else if (c == 1) src = hv0    + (size_t)(n0 + i) * DD;
            else if (c == 2) src = ebar_i + (size_t)(n0 + i) * DD;
            else             src = hub    + (size_t)smol[i] * DD;
            *reinterpret_cast<uint4*>(&xs[i * PITCH + c8]) =
                *reinterpret_cast<const uint4*>(src + c8);
        }
        __syncthreads();
#pragma unroll
        for (int ks = 0; ks < 4; ks++) {
            const unsigned short* wb = Wpk + ((c * 4 + ks) * 4 + quad) * 1024;
            s8b bfr[2];
#pragma unroll
            for (int nt = 0; nt < 2; nt++)
                bfr[nt] = *reinterpret_cast<const s8b*>(wb + (wv*32 + nt*16 + l15) * 8);
#pragma unroll
            for (int mt = 0; mt < 8; mt++) {
                s8b afr = *reinterpret_cast<const s8b*>(&xs[(mt*16 + l15) * PITCH + ks*32 + quad*8]);
#pragma unroll
                for (int nt = 0; nt < 2; nt++)
                    acc[mt][nt] = __builtin_amdgcn_mfma_f32_16x16x32_bf16(afr, bfr[nt], acc[mt][nt], 0, 0, 0);
            }
        }
        __syncthreads();
    }
#pragma unroll
    for (int nt = 0; nt < 2; nt++) {
        int col = wv*32 + nt*16 + l15;
        float bias = bvv[col];
#pragma unroll
        for (int mt = 0; mt < 8; mt++)
#pragma unroll
            for (int r = 0; r < 4; r++) {
                int row = n0 + mt*16 + quad*4 + r;
                hv[(size_t)row * DD + col] = f2us(fmaxf(acc[mt][nt][r] + bias, 0.f));
            }
    }
}

// ---------------- phi_u ----------------
__global__ void k_phi_u(const float* __restrict__ hu_in, const float* __restrict__ hu0,
                        const float* __restrict__ ebar, const float* __restrict__ vbar,
                        const float* __restrict__ Wu, const float* __restrict__ bu,
                        float* __restrict__ hu_out, unsigned short* __restrict__ hub_out,
                        float* __restrict__ dout) {
    int idx = blockIdx.x * 256 + threadIdx.x;   // M*D
    int m = idx >> 7, d = idx & 127;
    float acc = bu[d];
    const float* segs[4] = { hu_in + m*DD, hu0 + m*DD, ebar + m*DD, vbar + m*DD };
    for (int s = 0; s < 4; s++) {
        const float* x = segs[s];
        const float* W = Wu + (s*DD)*DD + d;
        for (int k = 0; k < DD; k++)
            acc = fmaf(x[k], W[k*DD], acc);
    }
    float v = fmaxf(acc, 0.f);
    hu_out[idx] = v;
    hub_out[idx] = f2us(v);
    dout[idx] = v;
}

// ---------------- launch ----------------

extern "C" void kernel_launch(void* const* d_in, const int* in_sizes, int n_in,
                              void* d_out, int out_size, void* d_ws, size_t ws_size,
                              hipStream_t stream) {
    const float* atoms = (const float*)d_in[0];
    const float* bo    = (const float*)d_in[1];
    const float* Wfe   = (const float*)d_in[2];
    const float* bfe   = (const float*)d_in[3];
    const float* Wfv   = (const float*)d_in[4];
    const float* bfv   = (const float*)d_in[5];
    const float* Wfu   = (const float*)d_in[6];
    const float* bfu   = (const float*)d_in[7];
    const float* We    = (const float*)d_in[8];
    const float* be    = (const float*)d_in[9];
    const float* Wv    = (const float*)d_in[10];
    const float* bv    = (const float*)d_in[11];
    const float* Wu    = (const float*)d_in[12];
    const float* bu    = (const float*)d_in[13];
    const int* bsrc    = (const int*)d_in[14];
    const int* bdst    = (const int*)d_in[15];
    const int* amol    = (const int*)d_in[16];
    const int* bmol    = (const int*)d_in[17];

    char* p = (char*)d_ws;
    auto alloc = [&](size_t bytes) {
        char* r = p;
        p += (bytes + 255) & ~(size_t)255;
        return r;
    };
    unsigned short* he     = (unsigned short*)alloc((size_t)N_BONDS * DD * 2);
    unsigned short* he0b   = (unsigned short*)alloc((size_t)N_BONDS * DD * 2);
    unsigned short* hv     = (unsigned short*)alloc((size_t)N_ATOMS * DD * 2);
    unsigned short* hv0b   = (unsigned short*)alloc((size_t)N_ATOMS * DD * 2);
    unsigned short* ebar_i = (unsigned short*)alloc((size_t)N_ATOMS * DD * 2);
    unsigned short* WeP    = (unsigned short*)alloc((size_t)640 * DD * 2);
    unsigned short* WvP    = (unsigned short*)alloc((size_t)512 * DD * 2);
    int* deg      = (int*)alloc((size_t)N_ATOMS * 4);
    int* rowptr   = (int*)alloc((size_t)(N_ATOMS + 1) * 4);
    int* cursor   = (int*)alloc((size_t)N_ATOMS * 4);
    int* adj      = (int*)alloc((size_t)2 * N_BONDS * 4);
    int* bmol_ptr = (int*)alloc((size_t)(N_MOLS + 1) * 4);
    int* amol_ptr = (int*)alloc((size_t)(N_MOLS + 1) * 4);
    float* node_sum = (float*)alloc((size_t)N_MOLS * DD * 4);
    float* hu0   = (float*)alloc((size_t)N_MOLS * DD * 4);
    float* huA   = (float*)alloc((size_t)N_MOLS * DD * 4);
    float* huB   = (float*)alloc((size_t)N_MOLS * DD * 4);
    float* ebar  = (float*)alloc((size_t)N_MOLS * DD * 4);
    float* vbar  = (float*)alloc((size_t)N_MOLS * DD * 4);
    unsigned short* hub0 = (unsigned short*)alloc((size_t)N_MOLS * DD * 2);
    unsigned short* hubA = (unsigned short*)alloc((size_t)N_MOLS * DD * 2);
    unsigned short* hubB = (unsigned short*)alloc((size_t)N_MOLS * DD * 2);

    // ---- CSR + mol ranges ----
    hipMemsetAsync(deg, 0, (size_t)N_ATOMS * 4, stream);
    k_deg<<<N_BONDS/256, 256, 0, stream>>>(bsrc, bdst, deg);
    k_scan<<<1, 1024, 0, stream>>>(deg, rowptr, cursor);
    k_fill<<<N_BONDS/256, 256, 0, stream>>>(bsrc, bdst, cursor, adj);
    k_molptr<<<1, 1024, 0, stream>>>(bmol, N_BONDS, bmol_ptr);
    k_molptr<<<1, 1024, 0, stream>>>(amol, N_ATOMS, amol_ptr);

    // ---- weight packing ----
    k_pack_w<<<(640*DD)/256, 256, 0, stream>>>(We, WeP, 640);
    k_pack_w<<<(512*DD)/256, 256, 0, stream>>>(Wv, WvP, 512);

    // ---- init ----
    k_init_edges<<<(N_BONDS*DD)/256, 256, 0, stream>>>(bo, Wfe, bfe, he, he0b);
    k_init_nodes<<<(N_ATOMS*DD)/256, 256, 0, stream>>>(atoms, Wfv, bfv, hv, hv0b);
    k_molsum<<<N_MOLS, 256, 0, stream>>>(hv, amol_ptr, node_sum);
    k_mol_init<<<(N_MOLS*DD)/256, 256, 0, stream>>>(node_sum, Wfu, bfu, hu0, hub0);

    const float* hu_in = hu0; float* hu_out = huA;
    const unsigned short* hub_in = hub0; unsigned short* hub_out = hubA;

    for (int r = 0; r < REPEAT; r++) {
        k_phi_e<<<N_BONDS/128, 256, 0, stream>>>(he, he0b, hv, hub_in, WeP, be,
                                                 bsrc, bdst, bmol);
        k_ebar<<<N_ATOMS/16, 256, 0, stream>>>(he, rowptr, adj, ebar_i);
        k_molsum<<<N_MOLS, 256, 0, stream>>>(he, bmol_ptr, ebar);
        k_phi_v<<<N_ATOMS/128, 256, 0, stream>>>(hv, hv0b, ebar_i, hub_in, WvP, bv, amol);
        k_molsum<<<N_MOLS, 256, 0, stream>>>(hv, amol_ptr, vbar);
        k_phi_u<<<(N_MOLS*DD)/256, 256, 0, stream>>>(hu_in, hu0, ebar, vbar, Wu, bu,
                                                     hu_out, hub_out, (float*)d_out);

        hu_in = hu_out;  hu_out  = (hu_out  == huA)  ? huB  : huA;
        hub_in = hub_out; hub_out = (hub_out == hubA) ? hubB : hubA;
    }
}